// Round 16
// baseline (116.945 us; speedup 1.0000x reference)
//
#include <hip/hip_runtime.h>
#include <hip/hip_bf16.h>

typedef __hip_bfloat16 bf16;
typedef __attribute__((ext_vector_type(8))) short short8;
typedef __attribute__((ext_vector_type(4))) float f32x4;
typedef __attribute__((ext_vector_type(16))) float f32x16;

// exp2-domain Q scale: log2(e) / sqrt(512)  (reference divides energies by sqrt(E))
static constexpr float QSCALE = 1.4426950408889634f / 22.627416997969522f;

__device__ __forceinline__ void gload_lds16(const void* g, void* l) {
  __builtin_amdgcn_global_load_lds((const __attribute__((address_space(1))) unsigned*)(g),
                                   (__attribute__((address_space(3))) unsigned*)(l), 16, 0, 0);
}

// one v_cvt_pk_bf16_f32: {lo16=bf16(a), hi16=bf16(b)} (T12 recipe, m214v22)
__device__ __forceinline__ unsigned cvtpk(float a, float b) {
  unsigned r;
  asm("v_cvt_pk_bf16_f32 %0, %1, %2" : "=v"(r) : "v"(a), "v"(b));
  return r;
}

// pack a 32-wide P row-slice (f32x16, this lane's 16 + partner's 16) into two
// B-operand bf16 fragments via cvt_pk + permlane32_swap (one swap fills 2 words)
__device__ __forceinline__ void packP(const f32x16& s, short8* pb) {
#pragma unroll
  for (int g = 0; g < 2; ++g) {
    unsigned a0 = cvtpk(s[8 * g + 0], s[8 * g + 1]);
    unsigned a1 = cvtpk(s[8 * g + 2], s[8 * g + 3]);
    unsigned b0 = cvtpk(s[8 * g + 4], s[8 * g + 5]);
    unsigned b1 = cvtpk(s[8 * g + 6], s[8 * g + 7]);
    asm("v_permlane32_swap_b32 %0, %1" : "+v"(a0), "+v"(b0));
    asm("v_permlane32_swap_b32 %0, %1" : "+v"(a1), "+v"(b1));
    union { unsigned u[4]; short8 v; } pu;
    pu.u[0] = a0; pu.u[1] = a1; pu.u[2] = b0; pu.u[3] = b1;
    pb[g] = pu.v;
  }
}

// ------ prep (weights only): Wqkv transpose+permute (0..191), Wproj (192..255).
// x conversion lives in gemm_qkv's A-staging (saves a full pass over x).
__global__ __launch_bounds__(256) void prep_w(const float* __restrict__ Wqkv,
                                              bf16* __restrict__ Wqkvt,
                                              const float* __restrict__ Wproj,
                                              bf16* __restrict__ Wprojt) {
  __shared__ float tile[64][65];
  const int bid = blockIdx.x;
  const float* W;
  bf16* Wt;
  int Nout, permute, j0, k0;
  if (bid < 192) {
    W = Wqkv; Wt = Wqkvt; Nout = 1536; permute = 1;
    j0 = (bid % 24) * 64; k0 = (bid / 24) * 64;
  } else {
    const int tb = bid - 192;
    W = Wproj; Wt = Wprojt; Nout = 512; permute = 0;
    j0 = (tb % 8) * 64; k0 = (tb / 8) * 64;
  }
  const int tx = threadIdx.x & 63, ty = threadIdx.x >> 6;
  for (int r = ty; r < 64; r += 4)
    tile[r][tx] = W[(size_t)(k0 + r) * Nout + j0 + tx];
  __syncthreads();
  for (int r = ty; r < 64; r += 4) {
    int j = j0 + r;
    int jp = j;
    if (permute) {
      int h = j / 192, rr = j % 192, d = rr / 3, s = rr % 3;
      jp = s * 512 + h * 64 + d;
    }
    Wt[(size_t)jp * 512 + k0 + tx] = __float2bfloat16(tile[tx][r]);
  }
}

// ------------- QKV GEMM: 128x128 tile, BK=64, XOR-swizzled LDS (T2) -------------
// A is read DIRECTLY from fp32 x: reg-staged (float4 x2 -> cvt_pk -> swizzled
// ds_write_b128). XCD decode (T1): same-bm blocks share bid%8 -> fp32 A working
// set per XCD stays L2-resident across the 12 bn re-reads.
__global__ __launch_bounds__(256, 3) void gemm_qkv(const float* __restrict__ X,
                                                   const bf16* __restrict__ Bt,
                                                   const float* __restrict__ bias,
                                                   bf16* __restrict__ Qb,
                                                   bf16* __restrict__ Kb,
                                                   bf16* __restrict__ Vt) {
  __shared__ short Alds[128 * 64];  // [row][8 chunks of 16B], slot cc holds logical chunk cc^(row&7)
  __shared__ short Blds[128 * 64];
  const int t = threadIdx.x;
  const int w = t >> 6;
  const int wr = w >> 1, wc = w & 1;
  const int lr = t & 15;
  const int lq = (t >> 4) & 3;
  const int bid = blockIdx.x;                // 0..767
  const int jj = bid >> 3;                   // 0..95
  const int bm = (bid & 7) + 8 * (jj / 12);  // same-bm blocks share bid%8 (XCD)
  const int bn = jj % 12;

  f32x4 acc[4][4];
#pragma unroll
  for (int m = 0; m < 4; ++m)
#pragma unroll
    for (int n = 0; n < 4; ++n)
#pragma unroll
      for (int j = 0; j < 4; ++j) acc[m][n][j] = 0.f;

  for (int kt = 0; kt < 8; ++kt) {
    // A: fp32 load + cvt + swizzled LDS write (1024 chunks, 4/thread)
#pragma unroll
    for (int i = 0; i < 4; ++i) {
      const int c = i * 256 + t, r = c >> 3, cc = c & 7, g = cc ^ (r & 7);
      const float* src = X + (size_t)(bm * 128 + r) * 512 + kt * 64 + cc * 8;
      const float4 a = *(const float4*)src;
      const float4 b2 = *(const float4*)(src + 4);
      union { short8 v; unsigned u[4]; } o;
      o.u[0] = cvtpk(a.x, a.y);
      o.u[1] = cvtpk(a.z, a.w);
      o.u[2] = cvtpk(b2.x, b2.y);
      o.u[3] = cvtpk(b2.z, b2.w);
      *(short8*)&Alds[r * 64 + g * 8] = o.v;
    }
    // B: bf16 async staging (source-pre-swizzled)
#pragma unroll
    for (int i = 0; i < 4; ++i) {
      const int c = i * 256 + t, r = c >> 3, g = (c & 7) ^ (r & 7);
      gload_lds16(Bt + (size_t)(bn * 128 + r) * 512 + kt * 64 + g * 8,
                  &Blds[(i * 256 + w * 64) * 8]);
    }
    __syncthreads();
#pragma unroll
    for (int kh2 = 0; kh2 < 2; ++kh2) {  // two K=32 halves of the BK=64 tile
      short8 af[4], bfr[4];
#pragma unroll
      for (int m = 0; m < 4; ++m)
        af[m] = *(const short8*)&Alds[(wr * 64 + m * 16 + lr) * 64 +
                                      ((((kh2 << 2) | lq) ^ (lr & 7)) << 3)];
#pragma unroll
      for (int n = 0; n < 4; ++n)
        bfr[n] = *(const short8*)&Blds[(wc * 64 + n * 16 + lr) * 64 +
                                       ((((kh2 << 2) | lq) ^ (lr & 7)) << 3)];
#pragma unroll
      for (int m = 0; m < 4; ++m)
#pragma unroll
        for (int n = 0; n < 4; ++n)
          acc[m][n] = __builtin_amdgcn_mfma_f32_16x16x32_bf16(af[m], bfr[n], acc[m][n], 0, 0, 0);
    }
    __syncthreads();
  }

#pragma unroll
  for (int m = 0; m < 4; ++m) {
#pragma unroll
    for (int n = 0; n < 4; ++n) {
      const int col = bn * 128 + wc * 64 + n * 16 + lr;
      const int s = col >> 9, h = (col >> 6) & 7, d = col & 63;
      const float bv = bias[h * 192 + d * 3 + s];
      const int hd = col & 511;
#pragma unroll
      for (int j = 0; j < 4; ++j) {
        const int row = bm * 128 + wr * 64 + m * 16 + lq * 4 + j;
        const float v = acc[m][n][j] + bv;
        if (s == 0)
          Qb[(size_t)row * 512 + hd] = __float2bfloat16(v * QSCALE);
        else if (s == 1)
          Kb[(size_t)row * 512 + hd] = __float2bfloat16(v);
        else
          Vt[((size_t)((row >> 11) * 8 + h) * 64 + d) * 2048 + (row & 2047)] =
              __float2bfloat16(v);
      }
    }
  }
}

// ------------- proj GEMM: 128x64 tile, BK=64, XOR-swizzled LDS -------------
__global__ __launch_bounds__(256, 2) void gemm_proj(const bf16* __restrict__ A,
                                                    const bf16* __restrict__ Bt,
                                                    const float* __restrict__ bias,
                                                    float* __restrict__ Cout) {
  __shared__ short Alds[128 * 64];  // 16 KB
  __shared__ short Blds[64 * 64];   // 8 KB
  const int t = threadIdx.x;
  const int w = t >> 6;
  const int wr = w >> 1, wc = w & 1;
  const int lr = t & 15;
  const int lq = (t >> 4) & 3;
  const int bid = blockIdx.x;                // 0..511
  const int jj = bid >> 3;                   // 0..63
  const int bm = (bid & 7) + 8 * (jj >> 3);  // 0..63
  const int bn = jj & 7;                     // 0..7

  f32x4 acc[4][2];
#pragma unroll
  for (int m = 0; m < 4; ++m)
#pragma unroll
    for (int n = 0; n < 2; ++n)
#pragma unroll
      for (int j = 0; j < 4; ++j) acc[m][n][j] = 0.f;

  for (int kt = 0; kt < 8; ++kt) {
#pragma unroll
    for (int i = 0; i < 4; ++i) {
      const int c = i * 256 + t, r = c >> 3, g = (c & 7) ^ (r & 7);
      gload_lds16(A + (size_t)(bm * 128 + r) * 512 + kt * 64 + g * 8,
                  &Alds[(i * 256 + w * 64) * 8]);
    }
#pragma unroll
    for (int i = 0; i < 2; ++i) {
      const int c = i * 256 + t, r = c >> 3, g = (c & 7) ^ (r & 7);
      gload_lds16(Bt + (size_t)(bn * 64 + r) * 512 + kt * 64 + g * 8,
                  &Blds[(i * 256 + w * 64) * 8]);
    }
    __syncthreads();
#pragma unroll
    for (int kh2 = 0; kh2 < 2; ++kh2) {
      short8 af[4], bfr[2];
#pragma unroll
      for (int m = 0; m < 4; ++m)
        af[m] = *(const short8*)&Alds[(wr * 64 + m * 16 + lr) * 64 +
                                      ((((kh2 << 2) | lq) ^ (lr & 7)) << 3)];
#pragma unroll
      for (int n = 0; n < 2; ++n)
        bfr[n] = *(const short8*)&Blds[(wc * 32 + n * 16 + lr) * 64 +
                                       ((((kh2 << 2) | lq) ^ (lr & 7)) << 3)];
#pragma unroll
      for (int m = 0; m < 4; ++m)
#pragma unroll
        for (int n = 0; n < 2; ++n)
          acc[m][n] = __builtin_amdgcn_mfma_f32_16x16x32_bf16(af[m], bfr[n], acc[m][n], 0, 0, 0);
    }
    __syncthreads();
  }

#pragma unroll
  for (int m = 0; m < 4; ++m) {
#pragma unroll
    for (int n = 0; n < 2; ++n) {
      const int col = bn * 64 + wc * 32 + n * 16 + lr;
      const float bv = bias[col];
#pragma unroll
      for (int j = 0; j < 4; ++j) {
        const int row = bm * 128 + wr * 64 + m * 16 + lq * 4 + j;
        Cout[(size_t)row * 512 + col] = acc[m][n][j] + bv;
      }
    }
  }
}

// ---- flash attention fwd: 2-wave blocks, key-split pair, KVBLK=64, grid 1024 ----
// Same per-wave work as R13/R15 (64 q-rows x 1024 keys, exact split-K merge, no
// max-shift) but 4 blocks/CU (LDS 33KB) -> 4 independent barrier groups per CU at
// the same 2 waves/SIMD: one group's serial chain (stage->QK->exp/pack->PV->bar)
// is covered by three others instead of one. Staging is per-block (2x redundant
// vs R15) but K/V are L2-resident.
__global__ __launch_bounds__(128, 4) void attn_fwd(const bf16* __restrict__ Q,
                                                   const bf16* __restrict__ K,
                                                   const bf16* __restrict__ Vt,
                                                   bf16* __restrict__ O) {
  __shared__ short Klds[2][64 * 64];  // [kv][d]  8 KB/buf
  __shared__ short Vlds[2][64 * 64];  // [d][kv]  8 KB/buf
  __shared__ float dnm[128];          // partial softmax denominators
  const int t = threadIdx.x;          // 0..127
  const int w = t >> 6;               // key-half of each 64-key tile
  const int l = t & 63;
  const int lo = l & 31;
  const int hi = l >> 5;
  const int bid = blockIdx.x;         // 0..1023
  const int bh = bid & 31, qt = bid >> 5;   // qt 0..31; bid%8 == bh%8 -> XCD-local K/V
  const int b = bh >> 3, h = bh & 7;
  const int qgA = qt * 64 + lo;       // q-group A rows; B = A + 32

  const bf16* Kb = K + (size_t)b * 2048 * 512 + h * 64;
  const bf16* Vb = Vt + (size_t)bh * 64 * 2048;

  // Q fragments (B-operand of QK^T): lane -> Q[q][d = kk*16 + hi*8 + 0..7]
  const bf16* qptrA = Q + ((size_t)b * 2048 + qgA) * 512 + h * 64 + hi * 8;
  short8 qfA[4], qfB[4];
#pragma unroll
  for (int kk = 0; kk < 4; ++kk) {
    qfA[kk] = *(const short8*)(qptrA + kk * 16);
    qfB[kk] = *(const short8*)(qptrA + 32 * 512 + kk * 16);
  }

  // all-ones bf16 A-operand for row-sum MFMA
  union { unsigned u[4]; short8 v; } ones;
#pragma unroll
  for (int j = 0; j < 4; ++j) ones.u[j] = 0x3F803F80u;

  // persistent zero vector: C-operand of first QK^T MFMA (kills 32 v_mov per QK)
  f32x16 zv;
#pragma unroll
  for (int r = 0; r < 16; ++r) zv[r] = 0.f;

  f32x16 accA0, accA1, accB0, accB1;  // partial O^T: [d = crow(r,hi) + 32*dt][q]
  f32x16 ssumA, ssumB;                // partial P row-sums (every reg = lsum for q=lo)
#pragma unroll
  for (int r = 0; r < 16; ++r) {
    accA0[r] = 0.f; accA1[r] = 0.f; accB0[r] = 0.f; accB1[r] = 0.f;
    ssumA[r] = 0.f; ssumB[r] = 0.f;
  }

  // staging (64-key tile): K = 512 chunks (64 rows x 8), V = 512 chunks
  // (64 rows x 8); 128 threads -> 4 chunks each per array, source-pre-swizzled.
#define STAGE(BUF, KV0)                                                              \
  do {                                                                               \
    _Pragma("unroll") for (int i = 0; i < 4; ++i) {                                  \
      const int c = i * 128 + t, r = c >> 3, g = (c & 7) ^ (r & 7);                  \
      gload_lds16(Kb + (size_t)((KV0) + r) * 512 + g * 8,                            \
                  &Klds[BUF][(i * 128 + w * 64) * 8]);                               \
    }                                                                                \
    _Pragma("unroll") for (int i = 0; i < 4; ++i) {                                  \
      const int c = i * 128 + t, r = c >> 3, g = (c & 7) ^ (r & 7);                  \
      gload_lds16(Vb + (size_t)r * 2048 + (KV0) + g * 8,                             \
                  &Vlds[BUF][(i * 128 + w * 64) * 8]);                               \
    }                                                                                \
  } while (0)

  STAGE(0, 0);
  __syncthreads();

#pragma unroll 2
  for (int it = 0; it < 32; ++it) {
    const int buf = it & 1;
    if (it + 1 < 32) STAGE(buf ^ 1, (it + 1) * 64);

    const char* kl = (const char*)&Klds[buf][0];
    const char* vl = (const char*)&Vlds[buf][0];

    // K fragments for THIS wave's 32-key half (rows w*32+lo; row&7 == lo&7)
    short8 kf[4];
#pragma unroll
    for (int kk = 0; kk < 4; ++kk)
      kf[kk] = *(const short8*)(kl + ((w * 32 + lo) << 7) +
                                ((((kk << 1) | hi) ^ (lo & 7)) << 4));

    // S^T = mfma(K, Q) for both q-groups; lane holds S[q=lo][k=crow(r,hi)]
    f32x16 sA, sB;
    __builtin_amdgcn_s_setprio(1);
#pragma unroll
    for (int kk = 0; kk < 4; ++kk) {
      sA = __builtin_amdgcn_mfma_f32_32x32x16_bf16(kf[kk], qfA[kk], kk ? sA : zv, 0, 0, 0);
      sB = __builtin_amdgcn_mfma_f32_32x32x16_bf16(kf[kk], qfB[kk], kk ? sB : zv, 0, 0, 0);
    }
    __builtin_amdgcn_s_setprio(0);

    // V^T fragments: row dt*32+lo (128B rows), chunk (w*4 + j*2 + hi)^(lo&7)
    short8 vf[2][2];
#pragma unroll
    for (int dt = 0; dt < 2; ++dt)
#pragma unroll
      for (int j = 0; j < 2; ++j)
        vf[dt][j] = *(const short8*)(vl + ((dt * 32 + lo) << 7) +
                                     ((((w << 2) | (j << 1) | hi) ^ (lo & 7)) << 4));

    // softmax numerator p = exp2(s) (scale folded into Q), single v_exp_f32 each
#pragma unroll
    for (int r = 0; r < 16; ++r) sA[r] = __builtin_amdgcn_exp2f(sA[r]);
#pragma unroll
    for (int r = 0; r < 16; ++r) sB[r] = __builtin_amdgcn_exp2f(sB[r]);
    short8 pbA[2], pbB[2];
    packP(sA, pbA);
    packP(sB, pbB);

    // partial O^T += V^T * P^T;  partial ssum += 1 * P^T
    __builtin_amdgcn_s_setprio(1);
#pragma unroll
    for (int j = 0; j < 2; ++j) {
      accA0 = __builtin_amdgcn_mfma_f32_32x32x16_bf16(vf[0][j], pbA[j], accA0, 0, 0, 0);
      accA1 = __builtin_amdgcn_mfma_f32_32x32x16_bf16(vf[1][j], pbA[j], accA1, 0, 0, 0);
      accB0 = __builtin_amdgcn_mfma_f32_32x32x16_bf16(vf[0][j], pbB[j], accB0, 0, 0, 0);
      accB1 = __builtin_amdgcn_mfma_f32_32x32x16_bf16(vf[1][j], pbB[j], accB1, 0, 0, 0);
      ssumA = __builtin_amdgcn_mfma_f32_32x32x16_bf16(ones.v, pbA[j], ssumA, 0, 0, 0);
      ssumB = __builtin_amdgcn_mfma_f32_32x32x16_bf16(ones.v, pbB[j], ssumB, 0, 0, 0);
    }
    __builtin_amdgcn_s_setprio(0);

    __syncthreads();  // drains vmcnt (next tile staged) + protects buffer reuse
  }
#undef STAGE

  // ---- split-K merge: wave 1 hands partials to wave 0 via LDS (exact add) ----
  float lsA = ssumA[0], lsB = ssumB[0];
  float* base = (float*)&Klds[0][0];  // 16 KB (both K buffers), exactly one wave's partials
  if (w) {
#pragma unroll
    for (int r = 0; r < 16; ++r) {  // rotate-indexed: bank = (r+l)%32, conflict-free
      base[l * 64 + ((r + l) & 63)] = accA0[r];
      base[l * 64 + ((16 + r + l) & 63)] = accA1[r];
      base[l * 64 + ((32 + r + l) & 63)] = accB0[r];
      base[l * 64 + ((48 + r + l) & 63)] = accB1[r];
    }
    dnm[l] = lsA;
    dnm[64 + l] = lsB;
  }
  __syncthreads();
  if (!w) {
#pragma unroll
    for (int r = 0; r < 16; ++r) {
      accA0[r] += base[l * 64 + ((r + l) & 63)];
      accA1[r] += base[l * 64 + ((16 + r + l) & 63)];
      accB0[r] += base[l * 64 + ((32 + r + l) & 63)];
      accB1[r] += base[l * 64 + ((48 + r + l) & 63)];
    }
    lsA += dnm[l];
    lsB += dnm[64 + l];
    const float rlA = 1.0f / lsA;
    const float rlB = 1.0f / lsB;
    bf16* opA = O + ((size_t)b * 2048 + qgA) * 512 + h * 64;
    bf16* opB = opA + 32 * 512;
#pragma unroll
    for (int r = 0; r < 16; ++r) {
      const int d = (r & 3) + 8 * (r >> 2) + 4 * hi;
      opA[d] = __float2bfloat16(accA0[r] * rlA);
      opA[32 + d] = __float2bfloat16(accA1[r] * rlA);
      opB[d] = __float2bfloat16(accB0[r] * rlB);
      opB[32 + d] = __float2bfloat16(accB1[r] * rlB);
    }
  }
}

// ---------------- launch ----------------
extern "C" void kernel_launch(void* const* d_in, const int* in_sizes, int n_in,
                              void* d_out, int out_size, void* d_ws, size_t ws_size,
                              hipStream_t stream) {
  const float* x = (const float*)d_in[0];      // [4,2048,512]
  const float* Wqkv = (const float*)d_in[1];   // [512,1536]
  const float* bqkv = (const float*)d_in[2];   // [1536]
  const float* Wproj = (const float*)d_in[3];  // [512,512]
  const float* bproj = (const float*)d_in[4];  // [512]
  float* out = (float*)d_out;                  // [4,2048,512] fp32

  char* ws = (char*)d_ws;
  bf16* Ob = (bf16*)ws;                       // 8192*512 (attn output)
  bf16* Wqkvt = Ob + (size_t)8192 * 512;      // 1536*512
  bf16* Wprojt = Wqkvt + (size_t)1536 * 512;  // 512*512
  bf16* Qb = Wprojt + (size_t)512 * 512;      // 8192*512
  bf16* Kb = Qb + (size_t)8192 * 512;         // 8192*512
  bf16* Vt = Kb + (size_t)8192 * 512;         // 32*64*2048

  prep_w<<<256, 256, 0, stream>>>(Wqkv, Wqkvt, Wproj, Wprojt);
  gemm_qkv<<<768, 256, 0, stream>>>(x, Wqkvt, bqkv, Qb, Kb, Vt);
  attn_fwd<<<1024, 128, 0, stream>>>(Qb, Kb, Vt, Ob);
  gemm_proj<<<512, 256, 0, stream>>>(Ob, Wprojt, bproj, out);
}

// Round 17
// 92.441 us; speedup vs baseline: 1.2651x; 1.2651x over previous
//
#include <hip/hip_runtime.h>
#include <hip/hip_bf16.h>

typedef __hip_bfloat16 bf16;
typedef __attribute__((ext_vector_type(8))) short short8;
typedef __attribute__((ext_vector_type(4))) float f32x4;
typedef __attribute__((ext_vector_type(16))) float f32x16;

// exp2-domain Q scale: log2(e) / sqrt(512)  (reference divides energies by sqrt(E))
static constexpr float QSCALE = 1.4426950408889634f / 22.627416997969522f;

__device__ __forceinline__ void gload_lds16(const void* g, void* l) {
  __builtin_amdgcn_global_load_lds((const __attribute__((address_space(1))) unsigned*)(g),
                                   (__attribute__((address_space(3))) unsigned*)(l), 16, 0, 0);
}

// one v_cvt_pk_bf16_f32: {lo16=bf16(a), hi16=bf16(b)} (T12 recipe, m214v22)
__device__ __forceinline__ unsigned cvtpk(float a, float b) {
  unsigned r;
  asm("v_cvt_pk_bf16_f32 %0, %1, %2" : "=v"(r) : "v"(a), "v"(b));
  return r;
}

// pack a 32-wide P row-slice (f32x16, this lane's 16 + partner's 16) into two
// B-operand bf16 fragments via cvt_pk + permlane32_swap (one swap fills 2 words)
__device__ __forceinline__ void packP(const f32x16& s, short8* pb) {
#pragma unroll
  for (int g = 0; g < 2; ++g) {
    unsigned a0 = cvtpk(s[8 * g + 0], s[8 * g + 1]);
    unsigned a1 = cvtpk(s[8 * g + 2], s[8 * g + 3]);
    unsigned b0 = cvtpk(s[8 * g + 4], s[8 * g + 5]);
    unsigned b1 = cvtpk(s[8 * g + 6], s[8 * g + 7]);
    asm("v_permlane32_swap_b32 %0, %1" : "+v"(a0), "+v"(b0));
    asm("v_permlane32_swap_b32 %0, %1" : "+v"(a1), "+v"(b1));
    union { unsigned u[4]; short8 v; } pu;
    pu.u[0] = a0; pu.u[1] = a1; pu.u[2] = b0; pu.u[3] = b1;
    pb[g] = pu.v;
  }
}

// ------ prep (weights only): Wqkv transpose+permute (0..191), Wproj (192..255).
// x conversion lives in gemm_qkv's A-staging (saves a full pass over x).
__global__ __launch_bounds__(256) void prep_w(const float* __restrict__ Wqkv,
                                              bf16* __restrict__ Wqkvt,
                                              const float* __restrict__ Wproj,
                                              bf16* __restrict__ Wprojt) {
  __shared__ float tile[64][65];
  const int bid = blockIdx.x;
  const float* W;
  bf16* Wt;
  int Nout, permute, j0, k0;
  if (bid < 192) {
    W = Wqkv; Wt = Wqkvt; Nout = 1536; permute = 1;
    j0 = (bid % 24) * 64; k0 = (bid / 24) * 64;
  } else {
    const int tb = bid - 192;
    W = Wproj; Wt = Wprojt; Nout = 512; permute = 0;
    j0 = (tb % 8) * 64; k0 = (tb / 8) * 64;
  }
  const int tx = threadIdx.x & 63, ty = threadIdx.x >> 6;
  for (int r = ty; r < 64; r += 4)
    tile[r][tx] = W[(size_t)(k0 + r) * Nout + j0 + tx];
  __syncthreads();
  for (int r = ty; r < 64; r += 4) {
    int j = j0 + r;
    int jp = j;
    if (permute) {
      int h = j / 192, rr = j % 192, d = rr / 3, s = rr % 3;
      jp = s * 512 + h * 64 + d;
    }
    Wt[(size_t)jp * 512 + k0 + tx] = __float2bfloat16(tile[tx][r]);
  }
}

// ------------- QKV GEMM: 128x128 tile, BK=64, XOR-swizzled LDS (T2) -------------
// A is read DIRECTLY from fp32 x: reg-staged (float4 x2 -> cvt_pk -> swizzled
// ds_write_b128). XCD decode (T1): same-bm blocks share bid%8 -> fp32 A working
// set per XCD stays L2-resident across the 12 bn re-reads.
__global__ __launch_bounds__(256, 3) void gemm_qkv(const float* __restrict__ X,
                                                   const bf16* __restrict__ Bt,
                                                   const float* __restrict__ bias,
                                                   bf16* __restrict__ Qb,
                                                   bf16* __restrict__ Kb,
                                                   bf16* __restrict__ Vt) {
  __shared__ short Alds[128 * 64];  // [row][8 chunks of 16B], slot cc holds logical chunk cc^(row&7)
  __shared__ short Blds[128 * 64];
  const int t = threadIdx.x;
  const int w = t >> 6;
  const int wr = w >> 1, wc = w & 1;
  const int lr = t & 15;
  const int lq = (t >> 4) & 3;
  const int bid = blockIdx.x;                // 0..767
  const int jj = bid >> 3;                   // 0..95
  const int bm = (bid & 7) + 8 * (jj / 12);  // same-bm blocks share bid%8 (XCD)
  const int bn = jj % 12;

  f32x4 acc[4][4];
#pragma unroll
  for (int m = 0; m < 4; ++m)
#pragma unroll
    for (int n = 0; n < 4; ++n)
#pragma unroll
      for (int j = 0; j < 4; ++j) acc[m][n][j] = 0.f;

  for (int kt = 0; kt < 8; ++kt) {
    // A: fp32 load + cvt + swizzled LDS write (1024 chunks, 4/thread)
#pragma unroll
    for (int i = 0; i < 4; ++i) {
      const int c = i * 256 + t, r = c >> 3, cc = c & 7, g = cc ^ (r & 7);
      const float* src = X + (size_t)(bm * 128 + r) * 512 + kt * 64 + cc * 8;
      const float4 a = *(const float4*)src;
      const float4 b2 = *(const float4*)(src + 4);
      union { short8 v; unsigned u[4]; } o;
      o.u[0] = cvtpk(a.x, a.y);
      o.u[1] = cvtpk(a.z, a.w);
      o.u[2] = cvtpk(b2.x, b2.y);
      o.u[3] = cvtpk(b2.z, b2.w);
      *(short8*)&Alds[r * 64 + g * 8] = o.v;
    }
    // B: bf16 async staging (source-pre-swizzled)
#pragma unroll
    for (int i = 0; i < 4; ++i) {
      const int c = i * 256 + t, r = c >> 3, g = (c & 7) ^ (r & 7);
      gload_lds16(Bt + (size_t)(bn * 128 + r) * 512 + kt * 64 + g * 8,
                  &Blds[(i * 256 + w * 64) * 8]);
    }
    __syncthreads();
#pragma unroll
    for (int kh2 = 0; kh2 < 2; ++kh2) {  // two K=32 halves of the BK=64 tile
      short8 af[4], bfr[4];
#pragma unroll
      for (int m = 0; m < 4; ++m)
        af[m] = *(const short8*)&Alds[(wr * 64 + m * 16 + lr) * 64 +
                                      ((((kh2 << 2) | lq) ^ (lr & 7)) << 3)];
#pragma unroll
      for (int n = 0; n < 4; ++n)
        bfr[n] = *(const short8*)&Blds[(wc * 64 + n * 16 + lr) * 64 +
                                       ((((kh2 << 2) | lq) ^ (lr & 7)) << 3)];
#pragma unroll
      for (int m = 0; m < 4; ++m)
#pragma unroll
        for (int n = 0; n < 4; ++n)
          acc[m][n] = __builtin_amdgcn_mfma_f32_16x16x32_bf16(af[m], bfr[n], acc[m][n], 0, 0, 0);
    }
    __syncthreads();
  }

#pragma unroll
  for (int m = 0; m < 4; ++m) {
#pragma unroll
    for (int n = 0; n < 4; ++n) {
      const int col = bn * 128 + wc * 64 + n * 16 + lr;
      const int s = col >> 9, h = (col >> 6) & 7, d = col & 63;
      const float bv = bias[h * 192 + d * 3 + s];
      const int hd = col & 511;
#pragma unroll
      for (int j = 0; j < 4; ++j) {
        const int row = bm * 128 + wr * 64 + m * 16 + lq * 4 + j;
        const float v = acc[m][n][j] + bv;
        if (s == 0)
          Qb[(size_t)row * 512 + hd] = __float2bfloat16(v * QSCALE);
        else if (s == 1)
          Kb[(size_t)row * 512 + hd] = __float2bfloat16(v);
        else
          Vt[((size_t)((row >> 11) * 8 + h) * 64 + d) * 2048 + (row & 2047)] =
              __float2bfloat16(v);
      }
    }
  }
}

// ------------- proj GEMM: 128x64 tile, BK=64, XOR-swizzled LDS -------------
__global__ __launch_bounds__(256, 2) void gemm_proj(const bf16* __restrict__ A,
                                                    const bf16* __restrict__ Bt,
                                                    const float* __restrict__ bias,
                                                    float* __restrict__ Cout) {
  __shared__ short Alds[128 * 64];  // 16 KB
  __shared__ short Blds[64 * 64];   // 8 KB
  const int t = threadIdx.x;
  const int w = t >> 6;
  const int wr = w >> 1, wc = w & 1;
  const int lr = t & 15;
  const int lq = (t >> 4) & 3;
  const int bid = blockIdx.x;                // 0..511
  const int jj = bid >> 3;                   // 0..63
  const int bm = (bid & 7) + 8 * (jj >> 3);  // 0..63
  const int bn = jj & 7;                     // 0..7

  f32x4 acc[4][2];
#pragma unroll
  for (int m = 0; m < 4; ++m)
#pragma unroll
    for (int n = 0; n < 2; ++n)
#pragma unroll
      for (int j = 0; j < 4; ++j) acc[m][n][j] = 0.f;

  for (int kt = 0; kt < 8; ++kt) {
#pragma unroll
    for (int i = 0; i < 4; ++i) {
      const int c = i * 256 + t, r = c >> 3, g = (c & 7) ^ (r & 7);
      gload_lds16(A + (size_t)(bm * 128 + r) * 512 + kt * 64 + g * 8,
                  &Alds[(i * 256 + w * 64) * 8]);
    }
#pragma unroll
    for (int i = 0; i < 2; ++i) {
      const int c = i * 256 + t, r = c >> 3, g = (c & 7) ^ (r & 7);
      gload_lds16(Bt + (size_t)(bn * 64 + r) * 512 + kt * 64 + g * 8,
                  &Blds[(i * 256 + w * 64) * 8]);
    }
    __syncthreads();
#pragma unroll
    for (int kh2 = 0; kh2 < 2; ++kh2) {
      short8 af[4], bfr[2];
#pragma unroll
      for (int m = 0; m < 4; ++m)
        af[m] = *(const short8*)&Alds[(wr * 64 + m * 16 + lr) * 64 +
                                      ((((kh2 << 2) | lq) ^ (lr & 7)) << 3)];
#pragma unroll
      for (int n = 0; n < 2; ++n)
        bfr[n] = *(const short8*)&Blds[(wc * 32 + n * 16 + lr) * 64 +
                                       ((((kh2 << 2) | lq) ^ (lr & 7)) << 3)];
#pragma unroll
      for (int m = 0; m < 4; ++m)
#pragma unroll
        for (int n = 0; n < 2; ++n)
          acc[m][n] = __builtin_amdgcn_mfma_f32_16x16x32_bf16(af[m], bfr[n], acc[m][n], 0, 0, 0);
    }
    __syncthreads();
  }

#pragma unroll
  for (int m = 0; m < 4; ++m) {
#pragma unroll
    for (int n = 0; n < 2; ++n) {
      const int col = bn * 64 + wc * 32 + n * 16 + lr;
      const float bv = bias[col];
#pragma unroll
      for (int j = 0; j < 4; ++j) {
        const int row = bm * 128 + wr * 64 + m * 16 + lq * 4 + j;
        Cout[(size_t)row * 512 + col] = acc[m][n][j] + bv;
      }
    }
  }
}

// ---- flash attention fwd: 4 waves/block, key-split wave pairs, KVBLK=128 ----
// (R13/R15 version — best measured: 49.0 us, VGPR 128, 2 waves/SIMD, no spill.)
__global__ __launch_bounds__(256, 2) void attn_fwd(const bf16* __restrict__ Q,
                                                   const bf16* __restrict__ K,
                                                   const bf16* __restrict__ Vt,
                                                   bf16* __restrict__ O) {
  __shared__ short Klds[2][128 * 64];  // [kv][d]  16 KB/buf
  __shared__ short Vlds[2][64 * 128];  // [d][kv]  16 KB/buf
  __shared__ float dnm[2][128];        // partial softmax denominators
  const int t = threadIdx.x;
  const int w = t >> 6;
  const int qw = w & 1;   // q-subtile
  const int kh = w >> 1;  // key-half of each 128-key tile
  const int l = t & 63;
  const int lo = l & 31;
  const int hi = l >> 5;
  const int bid = blockIdx.x;
  const int bh = bid & 31, qt = bid >> 5;
  const int b = bh >> 3, h = bh & 7;
  const int qgA = qt * 128 + qw * 64 + lo;  // q-group A rows; B = A + 32

  const bf16* Kb = K + (size_t)b * 2048 * 512 + h * 64;
  const bf16* Vb = Vt + (size_t)bh * 64 * 2048;

  // Q fragments (B-operand of QK^T): lane -> Q[q][d = kk*16 + hi*8 + 0..7]
  const bf16* qptrA = Q + ((size_t)b * 2048 + qgA) * 512 + h * 64 + hi * 8;
  short8 qfA[4], qfB[4];
#pragma unroll
  for (int kk = 0; kk < 4; ++kk) {
    qfA[kk] = *(const short8*)(qptrA + kk * 16);
    qfB[kk] = *(const short8*)(qptrA + 32 * 512 + kk * 16);
  }

  // all-ones bf16 A-operand for row-sum MFMA
  union { unsigned u[4]; short8 v; } ones;
#pragma unroll
  for (int j = 0; j < 4; ++j) ones.u[j] = 0x3F803F80u;

  // persistent zero vector: C-operand of first QK^T MFMA (kills 32 v_mov per QK)
  f32x16 zv;
#pragma unroll
  for (int r = 0; r < 16; ++r) zv[r] = 0.f;

  f32x16 accA0, accA1, accB0, accB1;  // partial O^T: [d = crow(r,hi) + 32*dt][q]
  f32x16 ssumA, ssumB;                // partial P row-sums (every reg = lsum for q=lo)
#pragma unroll
  for (int r = 0; r < 16; ++r) {
    accA0[r] = 0.f; accA1[r] = 0.f; accB0[r] = 0.f; accB1[r] = 0.f;
    ssumA[r] = 0.f; ssumB[r] = 0.f;
  }

  // staging (128-key tile): K = 1024 chunks (128 rows x 8), V = 1024 chunks
  // (64 rows x 16); 256 threads -> 4 chunks each per array, source-pre-swizzled.
#define STAGE(BUF, KV0)                                                              \
  do {                                                                               \
    _Pragma("unroll") for (int i = 0; i < 4; ++i) {                                  \
      const int c = i * 256 + t, r = c >> 3, g = (c & 7) ^ (r & 7);                  \
      gload_lds16(Kb + (size_t)((KV0) + r) * 512 + g * 8,                            \
                  &Klds[BUF][(i * 256 + w * 64) * 8]);                               \
    }                                                                                \
    _Pragma("unroll") for (int i = 0; i < 4; ++i) {                                  \
      const int c = i * 256 + t, r = c >> 4, g = (c & 15) ^ (r & 15);                \
      gload_lds16(Vb + (size_t)r * 2048 + (KV0) + g * 8,                             \
                  &Vlds[BUF][(i * 256 + w * 64) * 8]);                               \
    }                                                                                \
  } while (0)

  STAGE(0, 0);
  __syncthreads();

#pragma unroll 2
  for (int it = 0; it < 16; ++it) {
    const int buf = it & 1;
    if (it + 1 < 16) STAGE(buf ^ 1, (it + 1) * 128);

    const char* kl = (const char*)&Klds[buf][0];
    const char* vl = (const char*)&Vlds[buf][0];

#pragma unroll
    for (int sh = 0; sh < 2; ++sh) {  // 32-key substep: keys it*128 + kh*64 + sh*32 + lo
      // K fragments: row kh*64 + sh*32 + lo (row&7 == lo&7)
      short8 kf[4];
#pragma unroll
      for (int kk = 0; kk < 4; ++kk)
        kf[kk] = *(const short8*)(kl + ((kh * 64 + sh * 32 + lo) << 7) +
                                  ((((kk << 1) | hi) ^ (lo & 7)) << 4));

      // S^T = mfma(K, Q) for both q-groups; lane holds S[q=lo][k=crow(r,hi)]
      f32x16 sA, sB;
      __builtin_amdgcn_s_setprio(1);
#pragma unroll
      for (int kk = 0; kk < 4; ++kk) {
        sA = __builtin_amdgcn_mfma_f32_32x32x16_bf16(kf[kk], qfA[kk], kk ? sA : zv, 0, 0, 0);
        sB = __builtin_amdgcn_mfma_f32_32x32x16_bf16(kf[kk], qfB[kk], kk ? sB : zv, 0, 0, 0);
      }
      __builtin_amdgcn_s_setprio(0);

      // V^T fragments: row dt*32+lo (256B rows), chunk (kh*8+sh*4+j*2+hi)^(lo&15)
      short8 vf[2][2];
#pragma unroll
      for (int dt = 0; dt < 2; ++dt)
#pragma unroll
        for (int j = 0; j < 2; ++j)
          vf[dt][j] = *(const short8*)(vl + ((dt * 32 + lo) << 8) +
                                       ((((kh << 3) | (sh << 2) | (j << 1) | hi) ^ (lo & 15))
                                        << 4));

      // softmax numerator p = exp2(s) (scale folded into Q), single v_exp_f32 each
#pragma unroll
      for (int r = 0; r < 16; ++r) sA[r] = __builtin_amdgcn_exp2f(sA[r]);
#pragma unroll
      for (int r = 0; r < 16; ++r) sB[r] = __builtin_amdgcn_exp2f(sB[r]);
      short8 pbA[2], pbB[2];
      packP(sA, pbA);
      packP(sB, pbB);

      // partial O^T += V^T * P^T;  partial ssum += 1 * P^T
      __builtin_amdgcn_s_setprio(1);
#pragma unroll
      for (int j = 0; j < 2; ++j) {
        accA0 = __builtin_amdgcn_mfma_f32_32x32x16_bf16(vf[0][j], pbA[j], accA0, 0, 0, 0);
        accA1 = __builtin_amdgcn_mfma_f32_32x32x16_bf16(vf[1][j], pbA[j], accA1, 0, 0, 0);
        accB0 = __builtin_amdgcn_mfma_f32_32x32x16_bf16(vf[0][j], pbB[j], accB0, 0, 0, 0);
        accB1 = __builtin_amdgcn_mfma_f32_32x32x16_bf16(vf[1][j], pbB[j], accB1, 0, 0, 0);
        ssumA = __builtin_amdgcn_mfma_f32_32x32x16_bf16(ones.v, pbA[j], ssumA, 0, 0, 0);
        ssumB = __builtin_amdgcn_mfma_f32_32x32x16_bf16(ones.v, pbB[j], ssumB, 0, 0, 0);
      }
      __builtin_amdgcn_s_setprio(0);
    }

    __syncthreads();  // drains vmcnt (next tile staged) + protects buffer reuse
  }
#undef STAGE

  // ---- split-K merge: kh=1 waves hand partials to kh=0 waves via LDS (exact add) ----
  float lsA = ssumA[0], lsB = ssumB[0];
  float* base = qw ? (float*)&Vlds[0][0] : (float*)&Klds[0][0];  // 16 KB per q-subtile
  if (kh) {
#pragma unroll
    for (int r = 0; r < 16; ++r) {  // rotate-indexed: bank = (r+l)%32, conflict-free
      base[l * 64 + ((r + l) & 63)] = accA0[r];
      base[l * 64 + ((16 + r + l) & 63)] = accA1[r];
      base[l * 64 + ((32 + r + l) & 63)] = accB0[r];
      base[l * 64 + ((48 + r + l) & 63)] = accB1[r];
    }
    dnm[qw][l] = lsA;
    dnm[qw][64 + l] = lsB;
  }
  __syncthreads();
  if (!kh) {
#pragma unroll
    for (int r = 0; r < 16; ++r) {
      accA0[r] += base[l * 64 + ((r + l) & 63)];
      accA1[r] += base[l * 64 + ((16 + r + l) & 63)];
      accB0[r] += base[l * 64 + ((32 + r + l) & 63)];
      accB1[r] += base[l * 64 + ((48 + r + l) & 63)];
    }
    lsA += dnm[qw][l];
    lsB += dnm[qw][64 + l];
    const float rlA = 1.0f / lsA;
    const float rlB = 1.0f / lsB;
    bf16* opA = O + ((size_t)b * 2048 + qgA) * 512 + h * 64;
    bf16* opB = opA + 32 * 512;
#pragma unroll
    for (int r = 0; r < 16; ++r) {
      const int d = (r & 3) + 8 * (r >> 2) + 4 * hi;
      opA[d] = __float2bfloat16(accA0[r] * rlA);
      opA[32 + d] = __float2bfloat16(accA1[r] * rlA);
      opB[d] = __float2bfloat16(accB0[r] * rlB);
      opB[32 + d] = __float2bfloat16(accB1[r] * rlB);
    }
  }
}

// ---------------- launch ----------------
extern "C" void kernel_launch(void* const* d_in, const int* in_sizes, int n_in,
                              void* d_out, int out_size, void* d_ws, size_t ws_size,
                              hipStream_t stream) {
  const float* x = (const float*)d_in[0];      // [4,2048,512]
  const float* Wqkv = (const float*)d_in[1];   // [512,1536]
  const float* bqkv = (const float*)d_in[2];   // [1536]
  const float* Wproj = (const float*)d_in[3];  // [512,512]
  const float* bproj = (const float*)d_in[4];  // [512]
  float* out = (float*)d_out;                  // [4,2048,512] fp32

  char* ws = (char*)d_ws;
  bf16* Ob = (bf16*)ws;                       // 8192*512 (attn output)
  bf16* Wqkvt = Ob + (size_t)8192 * 512;      // 1536*512
  bf16* Wprojt = Wqkvt + (size_t)1536 * 512;  // 512*512
  bf16* Qb = Wprojt + (size_t)512 * 512;      // 8192*512
  bf16* Kb = Qb + (size_t)8192 * 512;         // 8192*512
  bf16* Vt = Kb + (size_t)8192 * 512;         // 32*64*2048

  prep_w<<<256, 256, 0, stream>>>(Wqkv, Wqkvt, Wproj, Wprojt);
  gemm_qkv<<<768, 256, 0, stream>>>(x, Wqkvt, bqkv, Qb, Kb, Vt);
  attn_fwd<<<512, 256, 0, stream>>>(Qb, Kb, Vt, Ob);
  gemm_proj<<<512, 256, 0, stream>>>(Ob, Wprojt, bproj, out);
}